// Round 1
// baseline (521.771 us; speedup 1.0000x reference)
//
#include <hip/hip_runtime.h>
#include <math.h>

#define D 128

// One block (256 threads = 4 waves) per segment.
// index is sorted ascending -> segment s occupies rows [lower_bound(s), lower_bound(s+1)).
// Since src = tanh(.) is in [-1,1], exp(src) never overflows, so the segment-max
// subtraction in the reference is a numerical no-op: we compute
//   out[s][d] = sum_r e_r * x[r][d] / (sum_r e_r + 1e-16),  e_r = exp(tanh(dot_r))
// in a single fused pass (x and ref each read exactly once from HBM).
__global__ __launch_bounds__(256) void attn_seg_kernel(
    const float* __restrict__ x,
    const float* __restrict__ ref,
    const int*   __restrict__ index,
    const float* __restrict__ W,
    const float* __restrict__ b,
    float*       __restrict__ out,
    int N)
{
    const int seg  = blockIdx.x;
    const int tid  = threadIdx.x;
    const int wave = tid >> 6;   // 0..3
    const int lane = tid & 63;   // 0..63

    // --- segment bounds via two lower_bounds (redundant per thread; uniform) ---
    int lo = 0, hi = N;
    while (lo < hi) { int mid = (lo + hi) >> 1; if (index[mid] < seg) lo = mid + 1; else hi = mid; }
    const int start = lo;
    hi = N;
    while (lo < hi) { int mid = (lo + hi) >> 1; if (index[mid] < seg + 1) lo = mid + 1; else hi = mid; }
    const int end = lo;

    // --- per-lane W fragment: lane l owns dims 2l, 2l+1 ---
    const float2 wx = ((const float2*)W)[lane];         // W[0:128]
    const float2 wr = ((const float2*)(W + D))[lane];   // W[128:256]
    const float bias = b[0];

    float2 acc = make_float2(0.f, 0.f);  // numerator partials for dims 2l, 2l+1
    float  sum_e = 0.f;                  // denominator partial (same on all lanes of wave)

    for (int r = start + wave; r < end; r += 4) {
        const size_t row = (size_t)r * D;
        const float2 xv = ((const float2*)(x   + row))[lane];
        const float2 rv = ((const float2*)(ref + row))[lane];
        float partial = xv.x * wx.x + xv.y * wx.y + rv.x * wr.x + rv.y * wr.y;
        #pragma unroll
        for (int off = 32; off >= 1; off >>= 1)
            partial += __shfl_xor(partial, off);         // full 64-lane reduce
        const float src = tanhf(partial + bias);
        const float e   = __expf(src);
        acc.x += e * xv.x;
        acc.y += e * xv.y;
        sum_e += e;
    }

    // --- cross-wave combine in LDS ---
    __shared__ float lds_acc[4][D];
    __shared__ float lds_sum[4];
    ((float2*)lds_acc[wave])[lane] = acc;   // dims 2l,2l+1 -> contiguous
    if (lane == 0) lds_sum[wave] = sum_e;
    __syncthreads();

    if (tid < D) {
        const float t = lds_acc[0][tid] + lds_acc[1][tid] + lds_acc[2][tid] + lds_acc[3][tid];
        const float s = lds_sum[0] + lds_sum[1] + lds_sum[2] + lds_sum[3] + 1e-16f;
        out[(size_t)seg * D + tid] = t / s;
    }
}

extern "C" void kernel_launch(void* const* d_in, const int* in_sizes, int n_in,
                              void* d_out, int out_size, void* d_ws, size_t ws_size,
                              hipStream_t stream) {
    const float* x     = (const float*)d_in[0];
    const float* ref   = (const float*)d_in[1];
    const int*   index = (const int*)d_in[2];
    // d_in[3] = batch_size (device scalar; B derived from out_size instead)
    const float* W     = (const float*)d_in[4];
    const float* b     = (const float*)d_in[5];
    float* out = (float*)d_out;

    const int N = in_sizes[0] / D;
    const int B = out_size / D;

    attn_seg_kernel<<<B, 256, 0, stream>>>(x, ref, index, W, b, out, N);
}

// Round 2
// 495.901 us; speedup vs baseline: 1.0522x; 1.0522x over previous
//
#include <hip/hip_runtime.h>
#include <math.h>

#define D 128

// --- Pass 1: segment start offsets from the sorted index array ---------------
// starts[j] = first row whose index >= j, for j in [0, B]; starts[B] = N.
// Union of (index[i-1], index[i]] over i plus the tail covers [0, B] exactly,
// so every entry is written every call (d_ws is re-poisoned before each launch).
__global__ __launch_bounds__(256) void seg_starts_kernel(
    const int* __restrict__ index, int* __restrict__ starts, int N, int B)
{
    int i = blockIdx.x * blockDim.x + threadIdx.x;
    if (i >= N) return;
    int cur  = index[i];
    int prev = (i == 0) ? -1 : index[i - 1];
    for (int j = prev + 1; j <= cur; ++j) starts[j] = i;
    if (i == N - 1) {
        for (int j = cur + 1; j <= B; ++j) starts[j] = N;
    }
}

// e = exp(tanh(v)); tanh(v) = 1 - 2/(1+exp(2v)). Correct limits at +/-inf:
// e2->inf => th->1 => e=e^1;  e2->0 => th->-1 => e=e^-1.
__device__ __forceinline__ float fast_exp_tanh(float v) {
    float e2 = __expf(2.0f * v);
    float th = 1.0f - 2.0f * __builtin_amdgcn_rcpf(1.0f + e2);
    return __expf(th);
}

// --- Pass 2: fused logit + segment softmax + weighted segment sum ------------
// One block (4 waves) per segment. Within a wave, lanes 0-31 handle row r,
// lanes 32-63 handle row r+1 (half-wave scheme): lane (hl, c) loads float4 of
// dims 4c..4c+3 -> the wave reads 1 KB contiguous per array per iteration and
// the dot-product butterfly is 5 steps (xor 16..1 stays within each half).
// src = tanh(.) is in [-1,1] so exp never overflows; the reference's
// segment-max subtraction is a numerical no-op and is dropped:
//   out[s][d] = sum_r e_r * x[r][d] / (sum_r e_r + 1e-16), e_r = exp(tanh(dot)).
__global__ __launch_bounds__(256) void attn_seg_kernel(
    const float* __restrict__ x,
    const float* __restrict__ ref,
    const int*   __restrict__ starts,
    const float* __restrict__ W,
    const float* __restrict__ b,
    float*       __restrict__ out)
{
    const int seg  = blockIdx.x;
    const int tid  = threadIdx.x;
    const int wave = tid >> 6;   // 0..3
    const int lane = tid & 63;
    const int hl   = lane >> 5;  // which row of the pair
    const int c    = lane & 31;  // column group: dims 4c..4c+3

    const int start = starts[seg];
    const int end   = starts[seg + 1];
    const int cnt   = end - start;

    const float4 wx = ((const float4*)W)[c];        // W[0:128] frag
    const float4 wr = ((const float4*)(W + D))[c];  // W[128:256] frag
    const float bias = b[0];

    float4 acc   = make_float4(0.f, 0.f, 0.f, 0.f);
    float  sum_e = 0.f;

    // Block covers 8 rows per iteration (4 waves x 2 half-rows), stride 8.
    const int niter = (cnt + 7) >> 3;
    const int rbase = start + (wave << 1) + hl;

    if (niter > 0) {
        const int last = end - 1;  // valid clamp target (cnt > 0 here)
        int cur_r = rbase;
        int row   = min(cur_r, last);
        float4 xv = ((const float4*)(x   + (size_t)row * D))[c];
        float4 rv = ((const float4*)(ref + (size_t)row * D))[c];

        for (int it = 1; it < niter; ++it) {
            // issue next iteration's loads before the reduce chain
            const int nxt_r = rbase + (it << 3);
            const int nrow  = min(nxt_r, last);
            float4 xn = ((const float4*)(x   + (size_t)nrow * D))[c];
            float4 rn = ((const float4*)(ref + (size_t)nrow * D))[c];

            float partial = xv.x*wx.x + xv.y*wx.y + xv.z*wx.z + xv.w*wx.w
                          + rv.x*wr.x + rv.y*wr.y + rv.z*wr.z + rv.w*wr.w;
            #pragma unroll
            for (int off = 16; off >= 1; off >>= 1)
                partial += __shfl_xor(partial, off);   // reduce within 32-lane half
            float e = fast_exp_tanh(partial + bias);
            e = (cur_r < end) ? e : 0.f;
            acc.x += e * xv.x; acc.y += e * xv.y;
            acc.z += e * xv.z; acc.w += e * xv.w;
            sum_e += e;

            xv = xn; rv = rn; cur_r = nxt_r;
        }

        // epilogue: last iteration
        float partial = xv.x*wx.x + xv.y*wx.y + xv.z*wx.z + xv.w*wx.w
                      + rv.x*wr.x + rv.y*wr.y + rv.z*wr.z + rv.w*wr.w;
        #pragma unroll
        for (int off = 16; off >= 1; off >>= 1)
            partial += __shfl_xor(partial, off);
        float e = fast_exp_tanh(partial + bias);
        e = (cur_r < end) ? e : 0.f;
        acc.x += e * xv.x; acc.y += e * xv.y;
        acc.z += e * xv.z; acc.w += e * xv.w;
        sum_e += e;
    }

    // --- combine 8 half-wave accumulators in LDS ---
    __shared__ float lds_acc[8][D];
    __shared__ float lds_sum[8];
    const int half_id = (wave << 1) | hl;
    ((float4*)lds_acc[half_id])[c] = acc;
    if (c == 0) lds_sum[half_id] = sum_e;
    __syncthreads();

    if (tid < D) {
        float t = 0.f;
        float s = 1e-16f;
        #pragma unroll
        for (int k = 0; k < 8; ++k) t += lds_acc[k][tid];
        #pragma unroll
        for (int k = 0; k < 8; ++k) s += lds_sum[k];
        out[(size_t)seg * D + tid] = t / s;
    }
}

extern "C" void kernel_launch(void* const* d_in, const int* in_sizes, int n_in,
                              void* d_out, int out_size, void* d_ws, size_t ws_size,
                              hipStream_t stream) {
    const float* x     = (const float*)d_in[0];
    const float* ref   = (const float*)d_in[1];
    const int*   index = (const int*)d_in[2];
    // d_in[3] = batch_size (device scalar; B derived from out_size instead)
    const float* W     = (const float*)d_in[4];
    const float* b     = (const float*)d_in[5];
    float* out = (float*)d_out;

    const int N = in_sizes[0] / D;
    const int B = out_size / D;

    int* starts = (int*)d_ws;  // B+1 ints

    seg_starts_kernel<<<(N + 255) / 256, 256, 0, stream>>>(index, starts, N, B);
    attn_seg_kernel<<<B, 256, 0, stream>>>(x, ref, starts, W, b, out);
}